// Round 3
// baseline (3079.073 us; speedup 1.0000x reference)
//
#include <hip/hip_runtime.h>

#define N_NODES 100000
#define E_EDGES 3200000
#define NG      512
#define BN_EPS  1e-5f

#define BSH     7                 // 128 nodes per bucket
#define BNODES  128
#define NBUCK   782               // ceil(100000/128)
#define NCHUNK  200
#define CHUNK   16000             // E_EDGES / NCHUNK

// ---------------- zero stats / pool accumulators ----------------
__global__ __launch_bounds__(256) void k_zero(float* __restrict__ stats1,
                                              float* __restrict__ stats2,
                                              float* __restrict__ sums,
                                              float* __restrict__ cnt) {
  int i = blockIdx.x * 256 + threadIdx.x;
  if (i < 128) { stats1[i] = 0.f; stats2[i] = 0.f; }
  if (i < NG * 64) sums[i] = 0.f;
  if (i < NG) cnt[i] = 0.f;
}

// ---------------- per-chunk bucket histogram (LDS, no global atomics) ----------------
__global__ __launch_bounds__(256) void kb_hist(const int* __restrict__ ei,
                                               int* __restrict__ counts) {
  __shared__ int h[NBUCK];
  const int c = blockIdx.x, tid = threadIdx.x;
  for (int b = tid; b < NBUCK; b += 256) h[b] = 0;
  __syncthreads();
  const int* dst = ei + E_EDGES + c * CHUNK;
  for (int i = tid; i < CHUNK; i += 256) atomicAdd(&h[dst[i] >> BSH], 1);
  __syncthreads();
  for (int b = tid; b < NBUCK; b += 256) counts[b * NCHUNK + c] = h[b];
}

// ---------------- scan 1: within-bucket exclusive scan over chunks ----------------
__global__ __launch_bounds__(256) void kb_scan1(int* __restrict__ counts,
                                                int* __restrict__ btot) {
  __shared__ int sm[256];
  const int b = blockIdx.x, tid = threadIdx.x;
  const int cval = (tid < NCHUNK) ? counts[b * NCHUNK + tid] : 0;
  int val = cval;
  sm[tid] = val;
  __syncthreads();
  for (int off = 1; off < 256; off <<= 1) {
    int t = (tid >= off) ? sm[tid - off] : 0;
    __syncthreads();
    val += t;
    sm[tid] = val;
    __syncthreads();
  }
  if (tid < NCHUNK) counts[b * NCHUNK + tid] = val - cval;
  if (tid == 255) btot[b] = val;
}

// ---------------- scan 2: exclusive scan of bucket totals ----------------
__global__ __launch_bounds__(1024) void kb_scan2(const int* __restrict__ btot,
                                                 int* __restrict__ bbase) {
  __shared__ int sm[1024];
  const int tid = threadIdx.x;
  const int cval = (tid < NBUCK) ? btot[tid] : 0;
  int val = cval;
  sm[tid] = val;
  __syncthreads();
  for (int off = 1; off < 1024; off <<= 1) {
    int t = (tid >= off) ? sm[tid - off] : 0;
    __syncthreads();
    val += t;
    sm[tid] = val;
    __syncthreads();
  }
  if (tid < NBUCK) bbase[tid] = val - cval;
  if (tid == NBUCK - 1) bbase[NBUCK] = val;  // == E_EDGES
}

// ---------------- partitioned scatter: pack (dstLocal<<17)|src into bucket runs ----------------
__global__ __launch_bounds__(256) void kb_scatter(const int* __restrict__ ei,
                                                  const int* __restrict__ counts,
                                                  const int* __restrict__ bbase,
                                                  int* __restrict__ binned) {
  __shared__ int cur[NBUCK];
  const int c = blockIdx.x, tid = threadIdx.x;
  for (int b = tid; b < NBUCK; b += 256) cur[b] = bbase[b] + counts[b * NCHUNK + c];
  __syncthreads();
  const int* srcp = ei + c * CHUNK;
  const int* dstp = ei + E_EDGES + c * CHUNK;
  for (int i = tid; i < CHUNK; i += 256) {
    const int s = srcp[i], d = dstp[i];
    const int pos = atomicAdd(&cur[d >> BSH], 1);
    binned[pos] = ((d & (BNODES - 1)) << 17) | s;
  }
}

// ---------------- per-bucket degree -> dis ----------------
__global__ __launch_bounds__(256) void kb_deg(const int* __restrict__ binned,
                                              const int* __restrict__ bbase,
                                              float* __restrict__ dis) {
  __shared__ int h[BNODES];
  const int b = blockIdx.x, tid = threadIdx.x;
  if (tid < BNODES) h[tid] = 0;
  __syncthreads();
  const int e0 = bbase[b], e1 = bbase[b + 1];
  for (int i = e0 + tid; i < e1; i += 256) atomicAdd(&h[binned[i] >> 17], 1);
  __syncthreads();
  if (tid < BNODES) {
    const int n = b * BNODES + tid;
    if (n < N_NODES) dis[n] = rsqrtf((float)(h[tid] + 1));  // +1 self loop
  }
}

// ---------------- GEMM: y[n][h] = dis[n] * sum_c in'[n][c]*W[c][h] ----------------
template <int K, bool BN>
__global__ __launch_bounds__(256) void k_gemm(const float* __restrict__ in,
                                              const float* __restrict__ W,
                                              const float* __restrict__ dis,
                                              const float* __restrict__ stats,
                                              const float* __restrict__ gam,
                                              const float* __restrict__ bet,
                                              float* __restrict__ y) {
  __shared__ float xs[32 * K];
  __shared__ float scv[64], shv[64];
  const int tid = threadIdx.x;
  const int n0 = blockIdx.x * 32;
  if (BN) {
    if (tid < 64) {
      const float m = stats[tid] * (1.0f / N_NODES);
      const float v = stats[64 + tid] * (1.0f / N_NODES) - m * m;
      const float sc = rsqrtf(v + BN_EPS) * gam[tid];
      scv[tid] = sc;
      shv[tid] = bet[tid] - m * sc;
    }
    __syncthreads();
  }
  const float4* in4 = (const float4*)(in + (size_t)n0 * K);
  float4* xs4 = (float4*)xs;
#pragma unroll
  for (int i = 0; i < (32 * K / 4) / 256; ++i) {
    float4 v = in4[tid + i * 256];
    if (BN) {
      const int c = ((tid + i * 256) * 4) & (K - 1);
      v.x = v.x * scv[c] + shv[c];
      v.y = v.y * scv[c + 1] + shv[c + 1];
      v.z = v.z * scv[c + 2] + shv[c + 2];
      v.w = v.w * scv[c + 3] + shv[c + 3];
    }
    xs4[tid + i * 256] = v;
  }
  __syncthreads();

  const int h = tid & 63, w = tid >> 6;
  float a[8] = {0, 0, 0, 0, 0, 0, 0, 0};
  for (int c = 0; c < K; c += 4) {
    const float w0 = W[(c + 0) * 64 + h];
    const float w1v = W[(c + 1) * 64 + h];
    const float w2v = W[(c + 2) * 64 + h];
    const float w3v = W[(c + 3) * 64 + h];
#pragma unroll
    for (int j = 0; j < 8; ++j) {
      const float4 xv = *(const float4*)&xs[(w + 4 * j) * K + c];
      a[j] = fmaf(xv.x, w0, fmaf(xv.y, w1v, fmaf(xv.z, w2v, fmaf(xv.w, w3v, a[j]))));
    }
  }
#pragma unroll
  for (int j = 0; j < 8; ++j) {
    const int n = n0 + w + 4 * j;
    y[(size_t)n * 64 + h] = dis[n] * a[j];
  }
}

// ---------------- bucket gather with LDS accumulator + conv epilogue ----------------
__global__ __launch_bounds__(256) void kb_gather(const int* __restrict__ binned,
                                                 const int* __restrict__ bbase,
                                                 const float* __restrict__ y,
                                                 const float* __restrict__ dis,
                                                 const float* __restrict__ bias,
                                                 float* __restrict__ hout,
                                                 float* __restrict__ stats) {
  __shared__ float acc[BNODES * 64];
  __shared__ float r1[256], r2[256];
  const int b = blockIdx.x, tid = threadIdx.x;
  const int lane = tid & 63;
  const int nbase = b * BNODES;
  // init accumulator with self-loop term y[n]
  for (int idx = tid; idx < BNODES * 64; idx += 256) {
    const int n = nbase + (idx >> 6);
    acc[idx] = (n < N_NODES) ? y[n * 64 + (idx & 63)] : 0.f;
  }
  __syncthreads();
  const int e0 = bbase[b], e1 = bbase[b + 1];
  const int total = e1 - e0;
  const int wv = tid >> 6;
  const int q0 = e0 + ((total * wv) >> 2);
  const int q1 = e0 + ((total * (wv + 1)) >> 2);
  int e = q0;
  for (; e + 4 <= q1; e += 4) {
    const int v0 = binned[e], v1 = binned[e + 1], v2 = binned[e + 2], v3 = binned[e + 3];
    const float f0 = y[(v0 & 0x1FFFF) * 64 + lane];
    const float f1 = y[(v1 & 0x1FFFF) * 64 + lane];
    const float f2 = y[(v2 & 0x1FFFF) * 64 + lane];
    const float f3 = y[(v3 & 0x1FFFF) * 64 + lane];
    atomicAdd(&acc[(v0 >> 17) * 64 + lane], f0);
    atomicAdd(&acc[(v1 >> 17) * 64 + lane], f1);
    atomicAdd(&acc[(v2 >> 17) * 64 + lane], f2);
    atomicAdd(&acc[(v3 >> 17) * 64 + lane], f3);
  }
  for (; e < q1; ++e) {
    const int v = binned[e];
    atomicAdd(&acc[(v >> 17) * 64 + lane], y[(v & 0x1FFFF) * 64 + lane]);
  }
  __syncthreads();
  const float bv = bias[lane];
  float s1 = 0.f, s2 = 0.f;
  for (int r = wv; r < BNODES; r += 4) {
    const int n = nbase + r;
    if (n >= N_NODES) break;
    float v = fmaxf(dis[n] * acc[r * 64 + lane] + bv, 0.f);
    hout[n * 64 + lane] = v;
    s1 += v;
    s2 += v * v;
  }
  r1[tid] = s1;
  r2[tid] = s2;
  __syncthreads();
  if (tid < 64) {
    atomicAdd(&stats[tid], r1[tid] + r1[tid + 64] + r1[tid + 128] + r1[tid + 192]);
  } else if (tid < 128) {
    const int h = tid - 64;
    atomicAdd(&stats[64 + h], r2[h] + r2[h + 64] + r2[h + 128] + r2[h + 192]);
  }
}

// ---------------- BN2 + mean-pool, run-length over sorted batch ----------------
__global__ __launch_bounds__(256) void k_pool(const float* __restrict__ hin,
                                              const float* __restrict__ stats,
                                              const float* __restrict__ gam,
                                              const float* __restrict__ bet,
                                              const int* __restrict__ batch,
                                              float* __restrict__ sums,
                                              float* __restrict__ cnt) {
  const int lane = threadIdx.x & 63;
  const int wid = (blockIdx.x * 256 + threadIdx.x) >> 6;
  const int nw = (gridDim.x * 256) >> 6;
  const int per = (N_NODES + nw - 1) / nw;
  const int n0 = wid * per;
  const int n1 = min(N_NODES, n0 + per);
  const float m = stats[lane] * (1.0f / N_NODES);
  const float v = stats[64 + lane] * (1.0f / N_NODES) - m * m;
  const float sc = rsqrtf(v + BN_EPS) * gam[lane];
  const float sh = bet[lane] - m * sc;
  int cur = -1, run = 0;
  float a = 0.f;
  for (int n = n0; n < n1; ++n) {
    const int b = batch[n];
    if (b != cur) {
      if (run) {
        atomicAdd(&sums[cur * 64 + lane], a);
        if (lane == 0) atomicAdd(&cnt[cur], (float)run);
      }
      cur = b; run = 0; a = 0.f;
    }
    a += hin[(size_t)n * 64 + lane] * sc + sh;
    ++run;
  }
  if (run) {
    atomicAdd(&sums[cur * 64 + lane], a);
    if (lane == 0) atomicAdd(&cnt[cur], (float)run);
  }
}

// ---------------- fused 5-layer MLP head, one block per graph ----------------
__global__ __launch_bounds__(128) void k_mlp(const float* __restrict__ sums,
                                             const float* __restrict__ cnt,
                                             const float* __restrict__ fw1, const float* __restrict__ fb1,
                                             const float* __restrict__ fw2, const float* __restrict__ fb2,
                                             const float* __restrict__ fw3, const float* __restrict__ fb3,
                                             const float* __restrict__ fw4, const float* __restrict__ fb4,
                                             const float* __restrict__ ow, const float* __restrict__ ob,
                                             float* __restrict__ out) {
  __shared__ float u0[128], u1[128];
  const int g = blockIdx.x, t = threadIdx.x;
  if (t < 64) u0[t] = sums[g * 64 + t] / fmaxf(cnt[g], 1.0f);
  __syncthreads();
  if (t < 128) {
    float a = fb1[t];
    for (int k = 0; k < 64; ++k) a = fmaf(u0[k], fw1[k * 128 + t], a);
    u1[t] = fmaxf(a, 0.f);
  }
  __syncthreads();
  if (t < 64) {
    float a = fb2[t];
    for (int k = 0; k < 128; ++k) a = fmaf(u1[k], fw2[k * 64 + t], a);
    u0[t] = fmaxf(a, 0.f);
  }
  __syncthreads();
  if (t < 32) {
    float a = fb3[t];
    for (int k = 0; k < 64; ++k) a = fmaf(u0[k], fw3[k * 32 + t], a);
    u1[t] = fmaxf(a, 0.f);
  }
  __syncthreads();
  if (t < 16) {
    float a = fb4[t];
    for (int k = 0; k < 32; ++k) a = fmaf(u1[k], fw4[k * 16 + t], a);
    u0[t] = fmaxf(a, 0.f);
  }
  __syncthreads();
  if (t < 2) {
    float a = ob[t];
    for (int k = 0; k < 16; ++k) a = fmaf(u0[k], ow[k * 2 + t], a);
    out[g * 2 + t] = a;
  }
}

extern "C" void kernel_launch(void* const* d_in, const int* in_sizes, int n_in,
                              void* d_out, int out_size, void* d_ws, size_t ws_size,
                              hipStream_t stream) {
  const float* x    = (const float*)d_in[0];
  const int*   ei   = (const int*)d_in[1];
  const int*   batch= (const int*)d_in[2];
  const float* w1   = (const float*)d_in[3];
  const float* b1   = (const float*)d_in[4];
  const float* w2   = (const float*)d_in[5];
  const float* b2   = (const float*)d_in[6];
  const float* g1   = (const float*)d_in[7];
  const float* be1  = (const float*)d_in[8];
  const float* g2   = (const float*)d_in[9];
  const float* be2  = (const float*)d_in[10];
  const float* fw1  = (const float*)d_in[11]; const float* fb1 = (const float*)d_in[12];
  const float* fw2  = (const float*)d_in[13]; const float* fb2 = (const float*)d_in[14];
  const float* fw3  = (const float*)d_in[15]; const float* fb3 = (const float*)d_in[16];
  const float* fw4  = (const float*)d_in[17]; const float* fb4 = (const float*)d_in[18];
  const float* ow   = (const float*)d_in[19]; const float* ob  = (const float*)d_in[20];
  float* out = (float*)d_out;

  char* ws = (char*)d_ws;
  auto alloc = [&](size_t bytes) {
    void* p = ws;
    ws += (bytes + 255) & ~(size_t)255;
    return p;
  };
  float* dis    = (float*)alloc((size_t)N_NODES * 4);
  int*   counts = (int*)  alloc((size_t)NBUCK * NCHUNK * 4);
  int*   btot   = (int*)  alloc((size_t)NBUCK * 4);
  int*   bbase  = (int*)  alloc((size_t)(NBUCK + 1) * 4);
  int*   binned = (int*)  alloc((size_t)E_EDGES * 4);
  float* bufA   = (float*)alloc((size_t)N_NODES * 64 * 4);
  float* bufB   = (float*)alloc((size_t)N_NODES * 64 * 4);
  float* bufC   = (float*)alloc((size_t)N_NODES * 64 * 4);
  float* stats1 = (float*)alloc(512);
  float* stats2 = (float*)alloc(512);
  float* sums   = (float*)alloc((size_t)NG * 64 * 4);
  float* cnt    = (float*)alloc((size_t)NG * 4);

  // zero accumulators; build bucket-binned edge list + dis (shared by both layers)
  k_zero    <<<128, 256, 0, stream>>>(stats1, stats2, sums, cnt);
  kb_hist   <<<NCHUNK, 256, 0, stream>>>(ei, counts);
  kb_scan1  <<<NBUCK, 256, 0, stream>>>(counts, btot);
  kb_scan2  <<<1, 1024, 0, stream>>>(btot, bbase);
  kb_scatter<<<NCHUNK, 256, 0, stream>>>(ei, counts, bbase, binned);
  kb_deg    <<<NBUCK, 256, 0, stream>>>(binned, bbase, dis);

  // conv1: y1 = dis*(x@w1) -> bufA; bucket gather -> h1raw=bufB + stats1
  k_gemm<256, false><<<N_NODES / 32, 256, 0, stream>>>(x, w1, dis, nullptr, nullptr, nullptr, bufA);
  kb_gather<<<NBUCK, 256, 0, stream>>>(binned, bbase, bufA, dis, b1, bufB, stats1);

  // conv2: y2 = dis*(BN1(h1raw)@w2) -> bufC; bucket gather -> h2raw=bufA + stats2
  k_gemm<64, true><<<N_NODES / 32, 256, 0, stream>>>(bufB, w2, dis, stats1, g1, be1, bufC);
  kb_gather<<<NBUCK, 256, 0, stream>>>(binned, bbase, bufC, dis, b2, bufA, stats2);

  // BN2 + pool (sorted batch, run-length) + MLP head
  k_pool<<<512, 256, 0, stream>>>(bufA, stats2, g2, be2, batch, sums, cnt);
  k_mlp <<<NG, 128, 0, stream>>>(sums, cnt, fw1, fb1, fw2, fb2, fw3, fb3, fw4, fb4, ow, ob, out);
}

// Round 4
// 725.504 us; speedup vs baseline: 4.2440x; 4.2440x over previous
//
#include <hip/hip_runtime.h>

#define N_NODES 100000
#define E_EDGES 3200000
#define NG      512
#define BN_EPS  1e-5f

#define BSH     7                 // 128 nodes per bucket
#define BNODES  128
#define NBUCK   782               // ceil(100000/128)
#define NCHUNK  200
#define CHUNK   16000             // E_EDGES / NCHUNK

// ---------------- zero stats / pool accumulators ----------------
__global__ __launch_bounds__(256) void k_zero(float* __restrict__ stats1,
                                              float* __restrict__ stats2,
                                              float* __restrict__ sums,
                                              float* __restrict__ cnt) {
  int i = blockIdx.x * 256 + threadIdx.x;
  if (i < 128) { stats1[i] = 0.f; stats2[i] = 0.f; }
  if (i < NG * 64) sums[i] = 0.f;
  if (i < NG) cnt[i] = 0.f;
}

// ---------------- per-chunk bucket histogram (LDS, no global atomics) ----------------
__global__ __launch_bounds__(256) void kb_hist(const int* __restrict__ ei,
                                               int* __restrict__ counts) {
  __shared__ int h[NBUCK];
  const int c = blockIdx.x, tid = threadIdx.x;
  for (int b = tid; b < NBUCK; b += 256) h[b] = 0;
  __syncthreads();
  const int* dst = ei + E_EDGES + c * CHUNK;
  for (int i = tid; i < CHUNK; i += 256) atomicAdd(&h[dst[i] >> BSH], 1);
  __syncthreads();
  for (int b = tid; b < NBUCK; b += 256) counts[b * NCHUNK + c] = h[b];
}

// ---------------- scan 1: within-bucket exclusive scan over chunks ----------------
__global__ __launch_bounds__(256) void kb_scan1(int* __restrict__ counts,
                                                int* __restrict__ btot) {
  __shared__ int sm[256];
  const int b = blockIdx.x, tid = threadIdx.x;
  const int cval = (tid < NCHUNK) ? counts[b * NCHUNK + tid] : 0;
  int val = cval;
  sm[tid] = val;
  __syncthreads();
  for (int off = 1; off < 256; off <<= 1) {
    int t = (tid >= off) ? sm[tid - off] : 0;
    __syncthreads();
    val += t;
    sm[tid] = val;
    __syncthreads();
  }
  if (tid < NCHUNK) counts[b * NCHUNK + tid] = val - cval;
  if (tid == 255) btot[b] = val;
}

// ---------------- scan 2: exclusive scan of bucket totals ----------------
__global__ __launch_bounds__(1024) void kb_scan2(const int* __restrict__ btot,
                                                 int* __restrict__ bbase) {
  __shared__ int sm[1024];
  const int tid = threadIdx.x;
  const int cval = (tid < NBUCK) ? btot[tid] : 0;
  int val = cval;
  sm[tid] = val;
  __syncthreads();
  for (int off = 1; off < 1024; off <<= 1) {
    int t = (tid >= off) ? sm[tid - off] : 0;
    __syncthreads();
    val += t;
    sm[tid] = val;
    __syncthreads();
  }
  if (tid < NBUCK) bbase[tid] = val - cval;
  if (tid == NBUCK - 1) bbase[NBUCK] = val;  // == E_EDGES
}

// ---------------- partitioned scatter: pack (dstLocal<<17)|src into bucket runs ----------------
__global__ __launch_bounds__(256) void kb_scatter(const int* __restrict__ ei,
                                                  const int* __restrict__ counts,
                                                  const int* __restrict__ bbase,
                                                  int* __restrict__ binned) {
  __shared__ int cur[NBUCK];
  const int c = blockIdx.x, tid = threadIdx.x;
  for (int b = tid; b < NBUCK; b += 256) cur[b] = bbase[b] + counts[b * NCHUNK + c];
  __syncthreads();
  const int* srcp = ei + c * CHUNK;
  const int* dstp = ei + E_EDGES + c * CHUNK;
  for (int i = tid; i < CHUNK; i += 256) {
    const int s = srcp[i], d = dstp[i];
    const int pos = atomicAdd(&cur[d >> BSH], 1);
    binned[pos] = ((d & (BNODES - 1)) << 17) | s;
  }
}

// ---------------- per-bucket counting sort -> CSR + row_start + dis ----------------
__global__ __launch_bounds__(256) void kb_degsort(const int* __restrict__ binned,
                                                  const int* __restrict__ bbase,
                                                  int* __restrict__ csr,
                                                  int* __restrict__ row_start,
                                                  float* __restrict__ dis) {
  __shared__ int h[BNODES];    // counts, then cursors
  __shared__ int pre[BNODES];  // inclusive prefix
  const int b = blockIdx.x, tid = threadIdx.x;
  if (tid < BNODES) h[tid] = 0;
  __syncthreads();
  const int e0 = bbase[b], e1 = bbase[b + 1];
  for (int i = e0 + tid; i < e1; i += 256) atomicAdd(&h[binned[i] >> 17], 1);
  __syncthreads();
  if (tid < BNODES) pre[tid] = h[tid];
  __syncthreads();
  for (int off = 1; off < BNODES; off <<= 1) {
    int t = (tid >= off && tid < BNODES) ? pre[tid - off] : 0;
    __syncthreads();
    if (tid < BNODES) pre[tid] += t;
    __syncthreads();
  }
  if (tid < BNODES) {
    const int n = b * BNODES + tid;
    const int ex = e0 + pre[tid] - h[tid];  // exclusive start for this node
    if (n < N_NODES) {
      row_start[n] = ex;
      dis[n] = rsqrtf((float)(h[tid] + 1));  // +1 self loop
    }
    h[tid] = ex;  // cursor
  }
  if (b == NBUCK - 1 && tid == 0) row_start[N_NODES] = E_EDGES;
  __syncthreads();
  for (int i = e0 + tid; i < e1; i += 256) {
    const int v = binned[i];
    const int pos = atomicAdd(&h[v >> 17], 1);
    csr[pos] = v & 0x1FFFF;  // writes stay inside this bucket's ~16KB window
  }
}

// ---------------- GEMM: y[n][h] = dis[n] * sum_c in'[n][c]*W[c][h] ----------------
template <int K, bool BN>
__global__ __launch_bounds__(256) void k_gemm(const float* __restrict__ in,
                                              const float* __restrict__ W,
                                              const float* __restrict__ dis,
                                              const float* __restrict__ stats,
                                              const float* __restrict__ gam,
                                              const float* __restrict__ bet,
                                              float* __restrict__ y) {
  __shared__ float xs[32 * K];
  __shared__ float scv[64], shv[64];
  const int tid = threadIdx.x;
  const int n0 = blockIdx.x * 32;
  if (BN) {
    if (tid < 64) {
      const float m = stats[tid] * (1.0f / N_NODES);
      const float v = stats[64 + tid] * (1.0f / N_NODES) - m * m;
      const float sc = rsqrtf(v + BN_EPS) * gam[tid];
      scv[tid] = sc;
      shv[tid] = bet[tid] - m * sc;
    }
    __syncthreads();
  }
  const float4* in4 = (const float4*)(in + (size_t)n0 * K);
  float4* xs4 = (float4*)xs;
#pragma unroll
  for (int i = 0; i < (32 * K / 4) / 256; ++i) {
    float4 v = in4[tid + i * 256];
    if (BN) {
      const int c = ((tid + i * 256) * 4) & (K - 1);
      v.x = v.x * scv[c] + shv[c];
      v.y = v.y * scv[c + 1] + shv[c + 1];
      v.z = v.z * scv[c + 2] + shv[c + 2];
      v.w = v.w * scv[c + 3] + shv[c + 3];
    }
    xs4[tid + i * 256] = v;
  }
  __syncthreads();

  const int h = tid & 63, w = tid >> 6;
  float a[8] = {0, 0, 0, 0, 0, 0, 0, 0};
  for (int c = 0; c < K; c += 4) {
    const float w0 = W[(c + 0) * 64 + h];
    const float w1v = W[(c + 1) * 64 + h];
    const float w2v = W[(c + 2) * 64 + h];
    const float w3v = W[(c + 3) * 64 + h];
#pragma unroll
    for (int j = 0; j < 8; ++j) {
      const float4 xv = *(const float4*)&xs[(w + 4 * j) * K + c];
      a[j] = fmaf(xv.x, w0, fmaf(xv.y, w1v, fmaf(xv.z, w2v, fmaf(xv.w, w3v, a[j]))));
    }
  }
#pragma unroll
  for (int j = 0; j < 8; ++j) {
    const int n = n0 + w + 4 * j;
    y[(size_t)n * 64 + h] = dis[n] * a[j];
  }
}

// ---------------- gather + conv epilogue: h = relu(dis*(y[n]+sum y[src]) + b), BN stats ----
__global__ __launch_bounds__(256) void k_gather(const int* __restrict__ csr,
                                                const int* __restrict__ rs,
                                                const float* __restrict__ y,
                                                const float* __restrict__ dis,
                                                const float* __restrict__ bias,
                                                float* __restrict__ hout,
                                                float* __restrict__ stats) {
  const int tid = threadIdx.x;
  const int lane = tid & 63;
  const int wid = (blockIdx.x * 256 + tid) >> 6;
  const int nw = (gridDim.x * 256) >> 6;
  const int per = (N_NODES + nw - 1) / nw;
  const int n0 = wid * per;
  const int n1 = min(N_NODES, n0 + per);
  const float b = bias[lane];
  float s1 = 0.f, s2 = 0.f;
  for (int n = n0; n < n1; ++n) {
    int e = rs[n];
    const int end = rs[n + 1];
    float a = y[(size_t)n * 64 + lane];
    float a2 = 0.f;
    for (; e + 4 <= end; e += 4) {
      const int i0 = csr[e], i1 = csr[e + 1], i2 = csr[e + 2], i3 = csr[e + 3];
      const float v0 = y[(size_t)i0 * 64 + lane];
      const float v1 = y[(size_t)i1 * 64 + lane];
      const float v2 = y[(size_t)i2 * 64 + lane];
      const float v3 = y[(size_t)i3 * 64 + lane];
      a += v0 + v1;
      a2 += v2 + v3;
    }
    for (; e < end; ++e) a += y[(size_t)csr[e] * 64 + lane];
    float v = fmaxf(dis[n] * (a + a2) + b, 0.f);
    hout[(size_t)n * 64 + lane] = v;
    s1 += v;
    s2 += v * v;
  }
  __shared__ float r1[256], r2[256];
  r1[tid] = s1;
  r2[tid] = s2;
  __syncthreads();
  if (tid < 64) {
    atomicAdd(&stats[tid], r1[tid] + r1[tid + 64] + r1[tid + 128] + r1[tid + 192]);
  } else if (tid < 128) {
    const int h = tid - 64;
    atomicAdd(&stats[64 + h], r2[h] + r2[h + 64] + r2[h + 128] + r2[h + 192]);
  }
}

// ---------------- BN2 + mean-pool, run-length over sorted batch ----------------
__global__ __launch_bounds__(256) void k_pool(const float* __restrict__ hin,
                                              const float* __restrict__ stats,
                                              const float* __restrict__ gam,
                                              const float* __restrict__ bet,
                                              const int* __restrict__ batch,
                                              float* __restrict__ sums,
                                              float* __restrict__ cnt) {
  const int lane = threadIdx.x & 63;
  const int wid = (blockIdx.x * 256 + threadIdx.x) >> 6;
  const int nw = (gridDim.x * 256) >> 6;
  const int per = (N_NODES + nw - 1) / nw;
  const int n0 = wid * per;
  const int n1 = min(N_NODES, n0 + per);
  const float m = stats[lane] * (1.0f / N_NODES);
  const float v = stats[64 + lane] * (1.0f / N_NODES) - m * m;
  const float sc = rsqrtf(v + BN_EPS) * gam[lane];
  const float sh = bet[lane] - m * sc;
  int cur = -1, run = 0;
  float a = 0.f;
  for (int n = n0; n < n1; ++n) {
    const int b = batch[n];
    if (b != cur) {
      if (run) {
        atomicAdd(&sums[cur * 64 + lane], a);
        if (lane == 0) atomicAdd(&cnt[cur], (float)run);
      }
      cur = b; run = 0; a = 0.f;
    }
    a += hin[(size_t)n * 64 + lane] * sc + sh;
    ++run;
  }
  if (run) {
    atomicAdd(&sums[cur * 64 + lane], a);
    if (lane == 0) atomicAdd(&cnt[cur], (float)run);
  }
}

// ---------------- fused 5-layer MLP head, one block per graph ----------------
__global__ __launch_bounds__(128) void k_mlp(const float* __restrict__ sums,
                                             const float* __restrict__ cnt,
                                             const float* __restrict__ fw1, const float* __restrict__ fb1,
                                             const float* __restrict__ fw2, const float* __restrict__ fb2,
                                             const float* __restrict__ fw3, const float* __restrict__ fb3,
                                             const float* __restrict__ fw4, const float* __restrict__ fb4,
                                             const float* __restrict__ ow, const float* __restrict__ ob,
                                             float* __restrict__ out) {
  __shared__ float u0[128], u1[128];
  const int g = blockIdx.x, t = threadIdx.x;
  if (t < 64) u0[t] = sums[g * 64 + t] / fmaxf(cnt[g], 1.0f);
  __syncthreads();
  if (t < 128) {
    float a = fb1[t];
    for (int k = 0; k < 64; ++k) a = fmaf(u0[k], fw1[k * 128 + t], a);
    u1[t] = fmaxf(a, 0.f);
  }
  __syncthreads();
  if (t < 64) {
    float a = fb2[t];
    for (int k = 0; k < 128; ++k) a = fmaf(u1[k], fw2[k * 64 + t], a);
    u0[t] = fmaxf(a, 0.f);
  }
  __syncthreads();
  if (t < 32) {
    float a = fb3[t];
    for (int k = 0; k < 64; ++k) a = fmaf(u0[k], fw3[k * 32 + t], a);
    u1[t] = fmaxf(a, 0.f);
  }
  __syncthreads();
  if (t < 16) {
    float a = fb4[t];
    for (int k = 0; k < 32; ++k) a = fmaf(u1[k], fw4[k * 16 + t], a);
    u0[t] = fmaxf(a, 0.f);
  }
  __syncthreads();
  if (t < 2) {
    float a = ob[t];
    for (int k = 0; k < 16; ++k) a = fmaf(u0[k], ow[k * 2 + t], a);
    out[g * 2 + t] = a;
  }
}

extern "C" void kernel_launch(void* const* d_in, const int* in_sizes, int n_in,
                              void* d_out, int out_size, void* d_ws, size_t ws_size,
                              hipStream_t stream) {
  const float* x    = (const float*)d_in[0];
  const int*   ei   = (const int*)d_in[1];
  const int*   batch= (const int*)d_in[2];
  const float* w1   = (const float*)d_in[3];
  const float* b1   = (const float*)d_in[4];
  const float* w2   = (const float*)d_in[5];
  const float* b2   = (const float*)d_in[6];
  const float* g1   = (const float*)d_in[7];
  const float* be1  = (const float*)d_in[8];
  const float* g2   = (const float*)d_in[9];
  const float* be2  = (const float*)d_in[10];
  const float* fw1  = (const float*)d_in[11]; const float* fb1 = (const float*)d_in[12];
  const float* fw2  = (const float*)d_in[13]; const float* fb2 = (const float*)d_in[14];
  const float* fw3  = (const float*)d_in[15]; const float* fb3 = (const float*)d_in[16];
  const float* fw4  = (const float*)d_in[17]; const float* fb4 = (const float*)d_in[18];
  const float* ow   = (const float*)d_in[19]; const float* ob  = (const float*)d_in[20];
  float* out = (float*)d_out;

  char* ws = (char*)d_ws;
  auto alloc = [&](size_t bytes) {
    void* p = ws;
    ws += (bytes + 255) & ~(size_t)255;
    return p;
  };
  float* dis      = (float*)alloc((size_t)N_NODES * 4);
  int*   counts   = (int*)  alloc((size_t)NBUCK * NCHUNK * 4);
  int*   btot     = (int*)  alloc((size_t)NBUCK * 4);
  int*   bbase    = (int*)  alloc((size_t)(NBUCK + 1) * 4);
  int*   binned   = (int*)  alloc((size_t)E_EDGES * 4);
  int*   csr      = (int*)  alloc((size_t)E_EDGES * 4);
  int*   row_start= (int*)  alloc((size_t)(N_NODES + 1) * 4);
  float* bufA     = (float*)alloc((size_t)N_NODES * 64 * 4);
  float* bufB     = (float*)alloc((size_t)N_NODES * 64 * 4);
  float* stats1   = (float*)alloc(512);
  float* stats2   = (float*)alloc(512);
  float* sums     = (float*)alloc((size_t)NG * 64 * 4);
  float* cnt      = (float*)alloc((size_t)NG * 4);

  // zero accumulators; build node-sorted CSR via bucket binning (shared by both layers)
  k_zero    <<<128, 256, 0, stream>>>(stats1, stats2, sums, cnt);
  kb_hist   <<<NCHUNK, 256, 0, stream>>>(ei, counts);
  kb_scan1  <<<NBUCK, 256, 0, stream>>>(counts, btot);
  kb_scan2  <<<1, 1024, 0, stream>>>(btot, bbase);
  kb_scatter<<<NCHUNK, 256, 0, stream>>>(ei, counts, bbase, binned);
  kb_degsort<<<NBUCK, 256, 0, stream>>>(binned, bbase, csr, row_start, dis);

  // conv1: y1 = dis*(x@w1) -> bufA; gather -> h1raw=bufB + stats1
  k_gemm<256, false><<<N_NODES / 32, 256, 0, stream>>>(x, w1, dis, nullptr, nullptr, nullptr, bufA);
  k_gather<<<2048, 256, 0, stream>>>(csr, row_start, bufA, dis, b1, bufB, stats1);

  // conv2: y2 = dis*(BN1(h1raw)@w2) -> bufA; gather -> h2=bufB + stats2
  k_gemm<64, true><<<N_NODES / 32, 256, 0, stream>>>(bufB, w2, dis, stats1, g1, be1, bufA);
  k_gather<<<2048, 256, 0, stream>>>(csr, row_start, bufA, dis, b2, bufB, stats2);

  // BN2 + pool (sorted batch, run-length) + MLP head
  k_pool<<<512, 256, 0, stream>>>(bufB, stats2, g2, be2, batch, sums, cnt);
  k_mlp <<<NG, 128, 0, stream>>>(sums, cnt, fw1, fb1, fw2, fb2, fw3, fb3, fw4, fb4, ow, ob, out);
}

// Round 5
// 680.376 us; speedup vs baseline: 4.5255x; 1.0663x over previous
//
#include <hip/hip_runtime.h>
#include <hip/hip_fp16.h>

#define N_NODES 100000
#define E_EDGES 3200000
#define NG      512
#define BN_EPS  1e-5f

#define BSH     7                 // 128 nodes per bucket
#define BNODES  128
#define NBUCK   782               // ceil(100000/128)
#define NCHUNK  200
#define CHUNK   16000             // E_EDGES / NCHUNK

// ---------------- zero stats / pool accumulators ----------------
__global__ __launch_bounds__(256) void k_zero(float* __restrict__ stats1,
                                              float* __restrict__ stats2,
                                              float* __restrict__ sums,
                                              float* __restrict__ cnt) {
  int i = blockIdx.x * 256 + threadIdx.x;
  if (i < 128) { stats1[i] = 0.f; stats2[i] = 0.f; }
  if (i < NG * 64) sums[i] = 0.f;
  if (i < NG) cnt[i] = 0.f;
}

// ---------------- per-chunk bucket histogram (LDS, no global atomics) ----------------
__global__ __launch_bounds__(256) void kb_hist(const int* __restrict__ ei,
                                               int* __restrict__ counts) {
  __shared__ int h[NBUCK];
  const int c = blockIdx.x, tid = threadIdx.x;
  for (int b = tid; b < NBUCK; b += 256) h[b] = 0;
  __syncthreads();
  const int* dst = ei + E_EDGES + c * CHUNK;
  for (int i = tid; i < CHUNK; i += 256) atomicAdd(&h[dst[i] >> BSH], 1);
  __syncthreads();
  for (int b = tid; b < NBUCK; b += 256) counts[b * NCHUNK + c] = h[b];
}

// ---------------- scan 1: within-bucket exclusive scan over chunks ----------------
__global__ __launch_bounds__(256) void kb_scan1(int* __restrict__ counts,
                                                int* __restrict__ btot) {
  __shared__ int sm[256];
  const int b = blockIdx.x, tid = threadIdx.x;
  const int cval = (tid < NCHUNK) ? counts[b * NCHUNK + tid] : 0;
  int val = cval;
  sm[tid] = val;
  __syncthreads();
  for (int off = 1; off < 256; off <<= 1) {
    int t = (tid >= off) ? sm[tid - off] : 0;
    __syncthreads();
    val += t;
    sm[tid] = val;
    __syncthreads();
  }
  if (tid < NCHUNK) counts[b * NCHUNK + tid] = val - cval;
  if (tid == 255) btot[b] = val;
}

// ---------------- scan 2: exclusive scan of bucket totals ----------------
__global__ __launch_bounds__(1024) void kb_scan2(const int* __restrict__ btot,
                                                 int* __restrict__ bbase) {
  __shared__ int sm[1024];
  const int tid = threadIdx.x;
  const int cval = (tid < NBUCK) ? btot[tid] : 0;
  int val = cval;
  sm[tid] = val;
  __syncthreads();
  for (int off = 1; off < 1024; off <<= 1) {
    int t = (tid >= off) ? sm[tid - off] : 0;
    __syncthreads();
    val += t;
    sm[tid] = val;
    __syncthreads();
  }
  if (tid < NBUCK) bbase[tid] = val - cval;
  if (tid == NBUCK - 1) bbase[NBUCK] = val;  // == E_EDGES
}

// ---------------- partitioned scatter: pack (dstLocal<<17)|src into bucket runs ----------------
__global__ __launch_bounds__(256) void kb_scatter(const int* __restrict__ ei,
                                                  const int* __restrict__ counts,
                                                  const int* __restrict__ bbase,
                                                  int* __restrict__ binned) {
  __shared__ int cur[NBUCK];
  const int c = blockIdx.x, tid = threadIdx.x;
  for (int b = tid; b < NBUCK; b += 256) cur[b] = bbase[b] + counts[b * NCHUNK + c];
  __syncthreads();
  const int* srcp = ei + c * CHUNK;
  const int* dstp = ei + E_EDGES + c * CHUNK;
  for (int i = tid; i < CHUNK; i += 256) {
    const int s = srcp[i], d = dstp[i];
    const int pos = atomicAdd(&cur[d >> BSH], 1);
    binned[pos] = ((d & (BNODES - 1)) << 17) | s;
  }
}

// ---------------- per-bucket counting sort -> CSR + row_start + dis ----------------
__global__ __launch_bounds__(256) void kb_degsort(const int* __restrict__ binned,
                                                  const int* __restrict__ bbase,
                                                  int* __restrict__ csr,
                                                  int* __restrict__ row_start,
                                                  float* __restrict__ dis) {
  __shared__ int h[BNODES];    // counts, then cursors
  __shared__ int pre[BNODES];  // inclusive prefix
  const int b = blockIdx.x, tid = threadIdx.x;
  if (tid < BNODES) h[tid] = 0;
  __syncthreads();
  const int e0 = bbase[b], e1 = bbase[b + 1];
  for (int i = e0 + tid; i < e1; i += 256) atomicAdd(&h[binned[i] >> 17], 1);
  __syncthreads();
  if (tid < BNODES) pre[tid] = h[tid];
  __syncthreads();
  for (int off = 1; off < BNODES; off <<= 1) {
    int t = (tid >= off && tid < BNODES) ? pre[tid - off] : 0;
    __syncthreads();
    if (tid < BNODES) pre[tid] += t;
    __syncthreads();
  }
  if (tid < BNODES) {
    const int n = b * BNODES + tid;
    const int ex = e0 + pre[tid] - h[tid];  // exclusive start for this node
    if (n < N_NODES) {
      row_start[n] = ex;
      dis[n] = rsqrtf((float)(h[tid] + 1));  // +1 self loop
    }
    h[tid] = ex;  // cursor
  }
  if (b == NBUCK - 1 && tid == 0) row_start[N_NODES] = E_EDGES;
  __syncthreads();
  for (int i = e0 + tid; i < e1; i += 256) {
    const int v = binned[i];
    const int pos = atomicAdd(&h[v >> 17], 1);
    csr[pos] = v & 0x1FFFF;  // writes stay inside this bucket's ~16KB window
  }
}

// ---------------- GEMM: y[n][h] = half(dis[n] * sum_c in'[n][c]*W[c][h]) --------------
// 64 nodes x 64 ch per block; thread = 4 nodes (stride 16) x 4 ch; K chunked by 64.
// xs row stride 68 floats -> odd float4-phase -> conflict-free b128 reads.
template <int K, bool BN>
__global__ __launch_bounds__(256) void k_gemm(const float* __restrict__ in,
                                              const float* __restrict__ W,
                                              const float* __restrict__ dis,
                                              const float* __restrict__ stats,
                                              const float* __restrict__ gam,
                                              const float* __restrict__ bet,
                                              __half* __restrict__ y) {
  __shared__ float xs[64 * 68];   // [n][c] padded (stride 68)
  __shared__ float wsm[64 * 64];  // [c][ch]
  __shared__ float scv[64], shv[64];
  const int tid = threadIdx.x;
  const int n0 = blockIdx.x * 64;
  const int lane = tid & 63, wv = tid >> 6;
  const int nq = lane & 15;                    // node phase: rows nq, nq+16, nq+32, nq+48
  const int chb = wv * 16 + (lane >> 4) * 4;   // channel base
  if (BN) {
    if (tid < 64) {
      const float m = stats[tid] * (1.0f / N_NODES);
      const float v = stats[64 + tid] * (1.0f / N_NODES) - m * m;
      const float sc = rsqrtf(v + BN_EPS) * gam[tid];
      scv[tid] = sc;
      shv[tid] = bet[tid] - m * sc;
    }
  }
  float a[4][4] = {{0,0,0,0},{0,0,0,0},{0,0,0,0},{0,0,0,0}};
  for (int c0 = 0; c0 < K; c0 += 64) {
    __syncthreads();
#pragma unroll
    for (int i = 0; i < 4; ++i) {  // stage x chunk: 64 n x 64 c
      const int idx = tid + i * 256;
      const int n = idx >> 4, c4 = (idx & 15) * 4;
      const int nn = min(n0 + n, N_NODES - 1);
      float4 v = *(const float4*)&in[(size_t)nn * K + c0 + c4];
      if (BN) {
        v.x = v.x * scv[c4] + shv[c4];
        v.y = v.y * scv[c4 + 1] + shv[c4 + 1];
        v.z = v.z * scv[c4 + 2] + shv[c4 + 2];
        v.w = v.w * scv[c4 + 3] + shv[c4 + 3];
      }
      *(float4*)&xs[n * 68 + c4] = v;
    }
#pragma unroll
    for (int i = 0; i < 4; ++i) {  // stage W chunk: 64 c x 64 ch
      const int idx = tid + i * 256;
      const int c = idx >> 4, ch4 = (idx & 15) * 4;
      *(float4*)&wsm[c * 64 + ch4] = *(const float4*)&W[(size_t)(c0 + c) * 64 + ch4];
    }
    __syncthreads();
    for (int c = 0; c < 64; c += 4) {
      float wq[4][4];
#pragma unroll
      for (int cc = 0; cc < 4; ++cc) {
        const float4 w4 = *(const float4*)&wsm[(c + cc) * 64 + chb];
        wq[cc][0] = w4.x; wq[cc][1] = w4.y; wq[cc][2] = w4.z; wq[cc][3] = w4.w;
      }
#pragma unroll
      for (int i = 0; i < 4; ++i) {
        const float4 xv = *(const float4*)&xs[(nq + 16 * i) * 68 + c];
#pragma unroll
        for (int j = 0; j < 4; ++j) {
          a[i][j] = fmaf(xv.x, wq[0][j],
                    fmaf(xv.y, wq[1][j],
                    fmaf(xv.z, wq[2][j],
                    fmaf(xv.w, wq[3][j], a[i][j]))));
        }
      }
    }
  }
#pragma unroll
  for (int i = 0; i < 4; ++i) {
    const int n = n0 + nq + 16 * i;
    if (n < N_NODES) {
      const float d = dis[n];
      union { __half h[4]; float2 f; } u;
      u.h[0] = __float2half_rn(d * a[i][0]);
      u.h[1] = __float2half_rn(d * a[i][1]);
      u.h[2] = __float2half_rn(d * a[i][2]);
      u.h[3] = __float2half_rn(d * a[i][3]);
      *(float2*)&y[(size_t)n * 64 + chb] = u.f;
    }
  }
}

// ---------------- gather + conv epilogue: h = relu(dis*(y[n]+sum y[src]) + b), BN stats ----
__global__ __launch_bounds__(256) void k_gather(const int* __restrict__ csr,
                                                const int* __restrict__ rs,
                                                const __half* __restrict__ y,
                                                const float* __restrict__ dis,
                                                const float* __restrict__ bias,
                                                float* __restrict__ hout,
                                                float* __restrict__ stats) {
  const int tid = threadIdx.x;
  const int lane = tid & 63;
  const int wid = (blockIdx.x * 256 + tid) >> 6;
  const int nw = (gridDim.x * 256) >> 6;
  const int per = (N_NODES + nw - 1) / nw;
  const int n0 = wid * per;
  const int n1 = min(N_NODES, n0 + per);
  const float b = bias[lane];
  float s1 = 0.f, s2 = 0.f;
  for (int n = n0; n < n1; ++n) {
    int e = rs[n];
    const int end = rs[n + 1];
    float a = __half2float(y[(size_t)n * 64 + lane]);
    float a2 = 0.f;
    for (; e + 4 <= end; e += 4) {
      const int i0 = csr[e], i1 = csr[e + 1], i2 = csr[e + 2], i3 = csr[e + 3];
      const float v0 = __half2float(y[(size_t)i0 * 64 + lane]);
      const float v1 = __half2float(y[(size_t)i1 * 64 + lane]);
      const float v2 = __half2float(y[(size_t)i2 * 64 + lane]);
      const float v3 = __half2float(y[(size_t)i3 * 64 + lane]);
      a += v0 + v1;
      a2 += v2 + v3;
    }
    for (; e < end; ++e) a += __half2float(y[(size_t)csr[e] * 64 + lane]);
    float v = fmaxf(dis[n] * (a + a2) + b, 0.f);
    hout[(size_t)n * 64 + lane] = v;
    s1 += v;
    s2 += v * v;
  }
  __shared__ float r1[256], r2[256];
  r1[tid] = s1;
  r2[tid] = s2;
  __syncthreads();
  if (tid < 64) {
    atomicAdd(&stats[tid], r1[tid] + r1[tid + 64] + r1[tid + 128] + r1[tid + 192]);
  } else if (tid < 128) {
    const int h = tid - 64;
    atomicAdd(&stats[64 + h], r2[h] + r2[h + 64] + r2[h + 128] + r2[h + 192]);
  }
}

// ---------------- BN2 + mean-pool, run-length over sorted batch ----------------
__global__ __launch_bounds__(256) void k_pool(const float* __restrict__ hin,
                                              const float* __restrict__ stats,
                                              const float* __restrict__ gam,
                                              const float* __restrict__ bet,
                                              const int* __restrict__ batch,
                                              float* __restrict__ sums,
                                              float* __restrict__ cnt) {
  const int lane = threadIdx.x & 63;
  const int wid = (blockIdx.x * 256 + threadIdx.x) >> 6;
  const int nw = (gridDim.x * 256) >> 6;
  const int per = (N_NODES + nw - 1) / nw;
  const int n0 = wid * per;
  const int n1 = min(N_NODES, n0 + per);
  const float m = stats[lane] * (1.0f / N_NODES);
  const float v = stats[64 + lane] * (1.0f / N_NODES) - m * m;
  const float sc = rsqrtf(v + BN_EPS) * gam[lane];
  const float sh = bet[lane] - m * sc;
  int cur = -1, run = 0;
  float a = 0.f;
  for (int n = n0; n < n1; ++n) {
    const int b = batch[n];
    if (b != cur) {
      if (run) {
        atomicAdd(&sums[cur * 64 + lane], a);
        if (lane == 0) atomicAdd(&cnt[cur], (float)run);
      }
      cur = b; run = 0; a = 0.f;
    }
    a += hin[(size_t)n * 64 + lane] * sc + sh;
    ++run;
  }
  if (run) {
    atomicAdd(&sums[cur * 64 + lane], a);
    if (lane == 0) atomicAdd(&cnt[cur], (float)run);
  }
}

// ---------------- fused 5-layer MLP head, one block per graph ----------------
__global__ __launch_bounds__(128) void k_mlp(const float* __restrict__ sums,
                                             const float* __restrict__ cnt,
                                             const float* __restrict__ fw1, const float* __restrict__ fb1,
                                             const float* __restrict__ fw2, const float* __restrict__ fb2,
                                             const float* __restrict__ fw3, const float* __restrict__ fb3,
                                             const float* __restrict__ fw4, const float* __restrict__ fb4,
                                             const float* __restrict__ ow, const float* __restrict__ ob,
                                             float* __restrict__ out) {
  __shared__ float u0[128], u1[128];
  const int g = blockIdx.x, t = threadIdx.x;
  if (t < 64) u0[t] = sums[g * 64 + t] / fmaxf(cnt[g], 1.0f);
  __syncthreads();
  if (t < 128) {
    float a = fb1[t];
    for (int k = 0; k < 64; ++k) a = fmaf(u0[k], fw1[k * 128 + t], a);
    u1[t] = fmaxf(a, 0.f);
  }
  __syncthreads();
  if (t < 64) {
    float a = fb2[t];
    for (int k = 0; k < 128; ++k) a = fmaf(u1[k], fw2[k * 64 + t], a);
    u0[t] = fmaxf(a, 0.f);
  }
  __syncthreads();
  if (t < 32) {
    float a = fb3[t];
    for (int k = 0; k < 64; ++k) a = fmaf(u0[k], fw3[k * 32 + t], a);
    u1[t] = fmaxf(a, 0.f);
  }
  __syncthreads();
  if (t < 16) {
    float a = fb4[t];
    for (int k = 0; k < 32; ++k) a = fmaf(u1[k], fw4[k * 16 + t], a);
    u0[t] = fmaxf(a, 0.f);
  }
  __syncthreads();
  if (t < 2) {
    float a = ob[t];
    for (int k = 0; k < 16; ++k) a = fmaf(u0[k], ow[k * 2 + t], a);
    out[g * 2 + t] = a;
  }
}

extern "C" void kernel_launch(void* const* d_in, const int* in_sizes, int n_in,
                              void* d_out, int out_size, void* d_ws, size_t ws_size,
                              hipStream_t stream) {
  const float* x    = (const float*)d_in[0];
  const int*   ei   = (const int*)d_in[1];
  const int*   batch= (const int*)d_in[2];
  const float* w1   = (const float*)d_in[3];
  const float* b1   = (const float*)d_in[4];
  const float* w2   = (const float*)d_in[5];
  const float* b2   = (const float*)d_in[6];
  const float* g1   = (const float*)d_in[7];
  const float* be1  = (const float*)d_in[8];
  const float* g2   = (const float*)d_in[9];
  const float* be2  = (const float*)d_in[10];
  const float* fw1  = (const float*)d_in[11]; const float* fb1 = (const float*)d_in[12];
  const float* fw2  = (const float*)d_in[13]; const float* fb2 = (const float*)d_in[14];
  const float* fw3  = (const float*)d_in[15]; const float* fb3 = (const float*)d_in[16];
  const float* fw4  = (const float*)d_in[17]; const float* fb4 = (const float*)d_in[18];
  const float* ow   = (const float*)d_in[19]; const float* ob  = (const float*)d_in[20];
  float* out = (float*)d_out;

  char* ws = (char*)d_ws;
  auto alloc = [&](size_t bytes) {
    void* p = ws;
    ws += (bytes + 255) & ~(size_t)255;
    return p;
  };
  float*  dis      = (float*)alloc((size_t)N_NODES * 4);
  int*    counts   = (int*)  alloc((size_t)NBUCK * NCHUNK * 4);
  int*    btot     = (int*)  alloc((size_t)NBUCK * 4);
  int*    bbase    = (int*)  alloc((size_t)(NBUCK + 1) * 4);
  int*    binned   = (int*)  alloc((size_t)E_EDGES * 4);
  int*    csr      = (int*)  alloc((size_t)E_EDGES * 4);
  int*    row_start= (int*)  alloc((size_t)(N_NODES + 1) * 4);
  __half* yH       = (__half*)alloc((size_t)N_NODES * 64 * 2);
  float*  hB       = (float*)alloc((size_t)N_NODES * 64 * 4);
  float*  stats1   = (float*)alloc(512);
  float*  stats2   = (float*)alloc(512);
  float*  sums     = (float*)alloc((size_t)NG * 64 * 4);
  float*  cnt      = (float*)alloc((size_t)NG * 4);

  const int nblkG = (N_NODES + 63) / 64;  // 1563 gemm blocks

  // zero accumulators; build node-sorted CSR via bucket binning (shared by both layers)
  k_zero    <<<128, 256, 0, stream>>>(stats1, stats2, sums, cnt);
  kb_hist   <<<NCHUNK, 256, 0, stream>>>(ei, counts);
  kb_scan1  <<<NBUCK, 256, 0, stream>>>(counts, btot);
  kb_scan2  <<<1, 1024, 0, stream>>>(btot, bbase);
  kb_scatter<<<NCHUNK, 256, 0, stream>>>(ei, counts, bbase, binned);
  kb_degsort<<<NBUCK, 256, 0, stream>>>(binned, bbase, csr, row_start, dis);

  // conv1: y1 = half(dis*(x@w1)) -> yH; gather -> h1raw=hB + stats1
  k_gemm<256, false><<<nblkG, 256, 0, stream>>>(x, w1, dis, nullptr, nullptr, nullptr, yH);
  k_gather<<<2048, 256, 0, stream>>>(csr, row_start, yH, dis, b1, hB, stats1);

  // conv2: y2 = half(dis*(BN1(h1raw)@w2)) -> yH; gather -> h2=hB + stats2
  k_gemm<64, true><<<nblkG, 256, 0, stream>>>(hB, w2, dis, stats1, g1, be1, yH);
  k_gather<<<2048, 256, 0, stream>>>(csr, row_start, yH, dis, b2, hB, stats2);

  // BN2 + pool (sorted batch, run-length) + MLP head
  k_pool<<<512, 256, 0, stream>>>(hB, stats2, g2, be2, batch, sums, cnt);
  k_mlp <<<NG, 128, 0, stream>>>(sums, cnt, fw1, fb1, fw2, fb2, fw3, fb3, fw4, fb4, ow, ob, out);
}

// Round 6
// 601.858 us; speedup vs baseline: 5.1159x; 1.1305x over previous
//
#include <hip/hip_runtime.h>
#include <hip/hip_fp16.h>

#define N_NODES 100000
#define E_EDGES 3200000
#define NG      512
#define BN_EPS  1e-5f

#define BSH     7                 // 128 nodes per bucket
#define BNODES  128
#define NBUCK   782               // ceil(100000/128)
#define NCHUNK  1024
#define CHUNK   3125              // E_EDGES / NCHUNK

// ---------------- zero stats / pool accumulators ----------------
__global__ __launch_bounds__(256) void k_zero(float* __restrict__ stats1,
                                              float* __restrict__ stats2,
                                              float* __restrict__ sums,
                                              float* __restrict__ cnt) {
  int i = blockIdx.x * 256 + threadIdx.x;
  if (i < 128) { stats1[i] = 0.f; stats2[i] = 0.f; }
  if (i < NG * 64) sums[i] = 0.f;
  if (i < NG) cnt[i] = 0.f;
}

// ---------------- per-chunk bucket histogram (LDS, no global atomics) ----------------
__global__ __launch_bounds__(256) void kb_hist(const int* __restrict__ ei,
                                               int* __restrict__ counts) {
  __shared__ int h[NBUCK];
  const int c = blockIdx.x, tid = threadIdx.x;
  for (int b = tid; b < NBUCK; b += 256) h[b] = 0;
  __syncthreads();
  const int* dst = ei + E_EDGES + c * CHUNK;
  for (int i = tid; i < CHUNK; i += 256) atomicAdd(&h[dst[i] >> BSH], 1);
  __syncthreads();
  for (int b = tid; b < NBUCK; b += 256) counts[b * NCHUNK + c] = h[b];
}

// ---------------- scan 1: within-bucket exclusive scan over chunks ----------------
__global__ __launch_bounds__(1024) void kb_scan1(int* __restrict__ counts,
                                                 int* __restrict__ btot) {
  __shared__ int sm[NCHUNK];
  const int b = blockIdx.x, tid = threadIdx.x;
  const int cval = counts[b * NCHUNK + tid];
  int val = cval;
  sm[tid] = val;
  __syncthreads();
  for (int off = 1; off < NCHUNK; off <<= 1) {
    int t = (tid >= off) ? sm[tid - off] : 0;
    __syncthreads();
    val += t;
    sm[tid] = val;
    __syncthreads();
  }
  counts[b * NCHUNK + tid] = val - cval;
  if (tid == NCHUNK - 1) btot[b] = val;
}

// ---------------- scan 2: exclusive scan of bucket totals ----------------
__global__ __launch_bounds__(1024) void kb_scan2(const int* __restrict__ btot,
                                                 int* __restrict__ bbase) {
  __shared__ int sm[1024];
  const int tid = threadIdx.x;
  const int cval = (tid < NBUCK) ? btot[tid] : 0;
  int val = cval;
  sm[tid] = val;
  __syncthreads();
  for (int off = 1; off < 1024; off <<= 1) {
    int t = (tid >= off) ? sm[tid - off] : 0;
    __syncthreads();
    val += t;
    sm[tid] = val;
    __syncthreads();
  }
  if (tid < NBUCK) bbase[tid] = val - cval;
  if (tid == NBUCK - 1) bbase[NBUCK] = val;  // == E_EDGES
}

// ---------------- partitioned scatter: pack (dstLocal<<17)|src into bucket runs ----------------
__global__ __launch_bounds__(256) void kb_scatter(const int* __restrict__ ei,
                                                  const int* __restrict__ counts,
                                                  const int* __restrict__ bbase,
                                                  int* __restrict__ binned) {
  __shared__ int cur[NBUCK];
  const int c = blockIdx.x, tid = threadIdx.x;
  for (int b = tid; b < NBUCK; b += 256) cur[b] = bbase[b] + counts[b * NCHUNK + c];
  __syncthreads();
  const int* srcp = ei + c * CHUNK;
  const int* dstp = ei + E_EDGES + c * CHUNK;
  for (int i = tid; i < CHUNK; i += 256) {
    const int s = srcp[i], d = dstp[i];
    const int pos = atomicAdd(&cur[d >> BSH], 1);
    binned[pos] = ((d & (BNODES - 1)) << 17) | s;
  }
}

// ---------------- per-bucket counting sort -> CSR + row_start + dis ----------------
__global__ __launch_bounds__(256) void kb_degsort(const int* __restrict__ binned,
                                                  const int* __restrict__ bbase,
                                                  int* __restrict__ csr,
                                                  int* __restrict__ row_start,
                                                  float* __restrict__ dis) {
  __shared__ int h[BNODES];    // counts, then cursors
  __shared__ int pre[BNODES];  // inclusive prefix
  const int b = blockIdx.x, tid = threadIdx.x;
  if (tid < BNODES) h[tid] = 0;
  __syncthreads();
  const int e0 = bbase[b], e1 = bbase[b + 1];
  for (int i = e0 + tid; i < e1; i += 256) atomicAdd(&h[binned[i] >> 17], 1);
  __syncthreads();
  if (tid < BNODES) pre[tid] = h[tid];
  __syncthreads();
  for (int off = 1; off < BNODES; off <<= 1) {
    int t = (tid >= off && tid < BNODES) ? pre[tid - off] : 0;
    __syncthreads();
    if (tid < BNODES) pre[tid] += t;
    __syncthreads();
  }
  if (tid < BNODES) {
    const int n = b * BNODES + tid;
    const int ex = e0 + pre[tid] - h[tid];  // exclusive start for this node
    if (n < N_NODES) {
      row_start[n] = ex;
      dis[n] = rsqrtf((float)(h[tid] + 1));  // +1 self loop
    }
    h[tid] = ex;  // cursor
  }
  if (b == NBUCK - 1 && tid == 0) row_start[N_NODES] = E_EDGES;
  __syncthreads();
  for (int i = e0 + tid; i < e1; i += 256) {
    const int v = binned[i];
    const int pos = atomicAdd(&h[v >> 17], 1);
    csr[pos] = v & 0x1FFFF;  // writes stay inside this bucket's ~16KB window
  }
}

// ---------------- GEMM: y[n][h] = half(dis[n] * sum_c in'[n][c]*W[c][h]) --------------
template <int K, bool BN>
__global__ __launch_bounds__(256) void k_gemm(const float* __restrict__ in,
                                              const float* __restrict__ W,
                                              const float* __restrict__ dis,
                                              const float* __restrict__ stats,
                                              const float* __restrict__ gam,
                                              const float* __restrict__ bet,
                                              __half* __restrict__ y) {
  __shared__ float xs[64 * 68];   // [n][c] padded (stride 68)
  __shared__ float wsm[64 * 64];  // [c][ch]
  __shared__ float scv[64], shv[64];
  const int tid = threadIdx.x;
  const int n0 = blockIdx.x * 64;
  const int lane = tid & 63, wv = tid >> 6;
  const int nq = lane & 15;
  const int chb = wv * 16 + (lane >> 4) * 4;
  if (BN) {
    if (tid < 64) {
      const float m = stats[tid] * (1.0f / N_NODES);
      const float v = stats[64 + tid] * (1.0f / N_NODES) - m * m;
      const float sc = rsqrtf(v + BN_EPS) * gam[tid];
      scv[tid] = sc;
      shv[tid] = bet[tid] - m * sc;
    }
  }
  float a[4][4] = {{0,0,0,0},{0,0,0,0},{0,0,0,0},{0,0,0,0}};
  for (int c0 = 0; c0 < K; c0 += 64) {
    __syncthreads();
#pragma unroll
    for (int i = 0; i < 4; ++i) {
      const int idx = tid + i * 256;
      const int n = idx >> 4, c4 = (idx & 15) * 4;
      const int nn = min(n0 + n, N_NODES - 1);
      float4 v = *(const float4*)&in[(size_t)nn * K + c0 + c4];
      if (BN) {
        v.x = v.x * scv[c4] + shv[c4];
        v.y = v.y * scv[c4 + 1] + shv[c4 + 1];
        v.z = v.z * scv[c4 + 2] + shv[c4 + 2];
        v.w = v.w * scv[c4 + 3] + shv[c4 + 3];
      }
      *(float4*)&xs[n * 68 + c4] = v;
    }
#pragma unroll
    for (int i = 0; i < 4; ++i) {
      const int idx = tid + i * 256;
      const int c = idx >> 4, ch4 = (idx & 15) * 4;
      *(float4*)&wsm[c * 64 + ch4] = *(const float4*)&W[(size_t)(c0 + c) * 64 + ch4];
    }
    __syncthreads();
    for (int c = 0; c < 64; c += 4) {
      float wq[4][4];
#pragma unroll
      for (int cc = 0; cc < 4; ++cc) {
        const float4 w4 = *(const float4*)&wsm[(c + cc) * 64 + chb];
        wq[cc][0] = w4.x; wq[cc][1] = w4.y; wq[cc][2] = w4.z; wq[cc][3] = w4.w;
      }
#pragma unroll
      for (int i = 0; i < 4; ++i) {
        const float4 xv = *(const float4*)&xs[(nq + 16 * i) * 68 + c];
#pragma unroll
        for (int j = 0; j < 4; ++j) {
          a[i][j] = fmaf(xv.x, wq[0][j],
                    fmaf(xv.y, wq[1][j],
                    fmaf(xv.z, wq[2][j],
                    fmaf(xv.w, wq[3][j], a[i][j]))));
        }
      }
    }
  }
#pragma unroll
  for (int i = 0; i < 4; ++i) {
    const int n = n0 + nq + 16 * i;
    if (n < N_NODES) {
      const float d = dis[n];
      union { __half h[4]; float2 f; } u;
      u.h[0] = __float2half_rn(d * a[i][0]);
      u.h[1] = __float2half_rn(d * a[i][1]);
      u.h[2] = __float2half_rn(d * a[i][2]);
      u.h[3] = __float2half_rn(d * a[i][3]);
      *(float2*)&y[(size_t)n * 64 + chb] = u.f;
    }
  }
}

// ---------------- dual-edge gather: lane = (edge parity p, channel pair c) ------------
// v = relu(dis*(y[n]+sum y[src]) + b); STORE mode writes hout, POOL mode run-length
// accumulates per-graph sums (BN2 is affine => applied later to pooled means).
template <bool POOL>
__global__ __launch_bounds__(256) void k_gather(const int* __restrict__ csr,
                                                const int* __restrict__ rs,
                                                const __half* __restrict__ y,
                                                const float* __restrict__ dis,
                                                const float* __restrict__ bias,
                                                float* __restrict__ hout,
                                                float* __restrict__ stats,
                                                const int* __restrict__ batch,
                                                float* __restrict__ sums,
                                                float* __restrict__ cnt) {
  const int tid = threadIdx.x;
  const int lane = tid & 63;
  const int p = lane >> 5;        // edge parity
  const int c = lane & 31;        // channel pair (channels 2c, 2c+1)
  const int wid = (blockIdx.x * 256 + tid) >> 6;
  const int nw = (gridDim.x * 256) >> 6;
  const int per = (N_NODES + nw - 1) / nw;
  const int n0 = wid * per;
  const int n1 = min(N_NODES, n0 + per);
  const float bx = bias[2 * c], by = bias[2 * c + 1];
  float s1x = 0.f, s1y = 0.f, s2x = 0.f, s2y = 0.f;
  int curg = -1, run = 0;
  float px = 0.f, py = 0.f;
  for (int n = n0; n < n1; ++n) {
    int e = rs[n];
    const int end = rs[n + 1];
    float ax = 0.f, ay = 0.f;
    if (p == 0) {  // self-loop term on parity-0 half
      const float2 f = __half22float2(*(const __half2*)&y[(size_t)n * 64 + 2 * c]);
      ax = f.x; ay = f.y;
    }
    for (; e + 8 <= end; e += 8) {
      const int i0 = csr[e + p];
      const int i1 = csr[e + 2 + p];
      const int i2 = csr[e + 4 + p];
      const int i3 = csr[e + 6 + p];
      const float2 f0 = __half22float2(*(const __half2*)&y[(size_t)i0 * 64 + 2 * c]);
      const float2 f1 = __half22float2(*(const __half2*)&y[(size_t)i1 * 64 + 2 * c]);
      const float2 f2 = __half22float2(*(const __half2*)&y[(size_t)i2 * 64 + 2 * c]);
      const float2 f3 = __half22float2(*(const __half2*)&y[(size_t)i3 * 64 + 2 * c]);
      ax += (f0.x + f1.x) + (f2.x + f3.x);
      ay += (f0.y + f1.y) + (f2.y + f3.y);
    }
    for (; e + 2 <= end; e += 2) {
      const int i0 = csr[e + p];
      const float2 f = __half22float2(*(const __half2*)&y[(size_t)i0 * 64 + 2 * c]);
      ax += f.x; ay += f.y;
    }
    if (e < end && p == 0) {  // odd leftover edge
      const int i0 = csr[e];
      const float2 f = __half22float2(*(const __half2*)&y[(size_t)i0 * 64 + 2 * c]);
      ax += f.x; ay += f.y;
    }
    ax += __shfl_xor(ax, 32);
    ay += __shfl_xor(ay, 32);
    const float d = dis[n];
    const float vx = fmaxf(d * ax + bx, 0.f);
    const float vy = fmaxf(d * ay + by, 0.f);
    if (lane < 32) {
      if (!POOL) *(float2*)&hout[(size_t)n * 64 + 2 * c] = make_float2(vx, vy);
      s1x += vx; s1y += vy;
      s2x += vx * vx; s2y += vy * vy;
    }
    if (POOL) {
      const int g = batch[n];
      if (g != curg) {
        if (run) {
          if (lane < 32) {
            atomicAdd(&sums[curg * 64 + 2 * c], px);
            atomicAdd(&sums[curg * 64 + 2 * c + 1], py);
          }
          if (lane == 0) atomicAdd(&cnt[curg], (float)run);
        }
        curg = g; run = 0; px = 0.f; py = 0.f;
      }
      if (lane < 32) { px += vx; py += vy; }
      ++run;
    }
  }
  if (POOL && run) {
    if (lane < 32) {
      atomicAdd(&sums[curg * 64 + 2 * c], px);
      atomicAdd(&sums[curg * 64 + 2 * c + 1], py);
    }
    if (lane == 0) atomicAdd(&cnt[curg], (float)run);
  }
  __shared__ float r1[256], r2[256];
  const int wv = tid >> 6;
  if (lane < 32) {
    r1[wv * 64 + 2 * c] = s1x; r1[wv * 64 + 2 * c + 1] = s1y;
    r2[wv * 64 + 2 * c] = s2x; r2[wv * 64 + 2 * c + 1] = s2y;
  }
  __syncthreads();
  if (tid < 64) {
    atomicAdd(&stats[tid], r1[tid] + r1[tid + 64] + r1[tid + 128] + r1[tid + 192]);
  } else if (tid < 128) {
    const int h = tid - 64;
    atomicAdd(&stats[64 + h], r2[h] + r2[h + 64] + r2[h + 128] + r2[h + 192]);
  }
}

// ---------------- fused BN2-affine + 5-layer MLP head, one block per graph ----------------
__global__ __launch_bounds__(128) void k_mlp(const float* __restrict__ sums,
                                             const float* __restrict__ cnt,
                                             const float* __restrict__ stats,
                                             const float* __restrict__ gam,
                                             const float* __restrict__ bet,
                                             const float* __restrict__ fw1, const float* __restrict__ fb1,
                                             const float* __restrict__ fw2, const float* __restrict__ fb2,
                                             const float* __restrict__ fw3, const float* __restrict__ fb3,
                                             const float* __restrict__ fw4, const float* __restrict__ fb4,
                                             const float* __restrict__ ow, const float* __restrict__ ob,
                                             float* __restrict__ out) {
  __shared__ float u0[128], u1[128];
  const int g = blockIdx.x, t = threadIdx.x;
  if (t < 64) {
    const float m = stats[t] * (1.0f / N_NODES);
    const float v = stats[64 + t] * (1.0f / N_NODES) - m * m;
    const float sc = rsqrtf(v + BN_EPS) * gam[t];
    const float sh = bet[t] - m * sc;
    u0[t] = (sums[g * 64 + t] / fmaxf(cnt[g], 1.0f)) * sc + sh;  // BN affine on pooled mean
  }
  __syncthreads();
  if (t < 128) {
    float a = fb1[t];
    for (int k = 0; k < 64; ++k) a = fmaf(u0[k], fw1[k * 128 + t], a);
    u1[t] = fmaxf(a, 0.f);
  }
  __syncthreads();
  if (t < 64) {
    float a = fb2[t];
    for (int k = 0; k < 128; ++k) a = fmaf(u1[k], fw2[k * 64 + t], a);
    u0[t] = fmaxf(a, 0.f);
  }
  __syncthreads();
  if (t < 32) {
    float a = fb3[t];
    for (int k = 0; k < 64; ++k) a = fmaf(u0[k], fw3[k * 32 + t], a);
    u1[t] = fmaxf(a, 0.f);
  }
  __syncthreads();
  if (t < 16) {
    float a = fb4[t];
    for (int k = 0; k < 32; ++k) a = fmaf(u1[k], fw4[k * 16 + t], a);
    u0[t] = fmaxf(a, 0.f);
  }
  __syncthreads();
  if (t < 2) {
    float a = ob[t];
    for (int k = 0; k < 16; ++k) a = fmaf(u0[k], ow[k * 2 + t], a);
    out[g * 2 + t] = a;
  }
}

extern "C" void kernel_launch(void* const* d_in, const int* in_sizes, int n_in,
                              void* d_out, int out_size, void* d_ws, size_t ws_size,
                              hipStream_t stream) {
  const float* x    = (const float*)d_in[0];
  const int*   ei   = (const int*)d_in[1];
  const int*   batch= (const int*)d_in[2];
  const float* w1   = (const float*)d_in[3];
  const float* b1   = (const float*)d_in[4];
  const float* w2   = (const float*)d_in[5];
  const float* b2   = (const float*)d_in[6];
  const float* g1   = (const float*)d_in[7];
  const float* be1  = (const float*)d_in[8];
  const float* g2   = (const float*)d_in[9];
  const float* be2  = (const float*)d_in[10];
  const float* fw1  = (const float*)d_in[11]; const float* fb1 = (const float*)d_in[12];
  const float* fw2  = (const float*)d_in[13]; const float* fb2 = (const float*)d_in[14];
  const float* fw3  = (const float*)d_in[15]; const float* fb3 = (const float*)d_in[16];
  const float* fw4  = (const float*)d_in[17]; const float* fb4 = (const float*)d_in[18];
  const float* ow   = (const float*)d_in[19]; const float* ob  = (const float*)d_in[20];
  float* out = (float*)d_out;

  char* ws = (char*)d_ws;
  auto alloc = [&](size_t bytes) {
    void* p = ws;
    ws += (bytes + 255) & ~(size_t)255;
    return p;
  };
  float*  dis      = (float*)alloc((size_t)N_NODES * 4);
  int*    counts   = (int*)  alloc((size_t)NBUCK * NCHUNK * 4);
  int*    btot     = (int*)  alloc((size_t)NBUCK * 4);
  int*    bbase    = (int*)  alloc((size_t)(NBUCK + 1) * 4);
  int*    binned   = (int*)  alloc((size_t)E_EDGES * 4);
  int*    csr      = (int*)  alloc((size_t)E_EDGES * 4);
  int*    row_start= (int*)  alloc((size_t)(N_NODES + 1) * 4);
  __half* yH       = (__half*)alloc((size_t)N_NODES * 64 * 2);
  float*  hB       = (float*)alloc((size_t)N_NODES * 64 * 4);
  float*  stats1   = (float*)alloc(512);
  float*  stats2   = (float*)alloc(512);
  float*  sums     = (float*)alloc((size_t)NG * 64 * 4);
  float*  cnt      = (float*)alloc((size_t)NG * 4);

  const int nblkG = (N_NODES + 63) / 64;

  // zero accumulators; build node-sorted CSR via bucket binning (shared by both layers)
  k_zero    <<<128, 256, 0, stream>>>(stats1, stats2, sums, cnt);
  kb_hist   <<<NCHUNK, 256, 0, stream>>>(ei, counts);
  kb_scan1  <<<NBUCK, NCHUNK, 0, stream>>>(counts, btot);
  kb_scan2  <<<1, 1024, 0, stream>>>(btot, bbase);
  kb_scatter<<<NCHUNK, 256, 0, stream>>>(ei, counts, bbase, binned);
  kb_degsort<<<NBUCK, 256, 0, stream>>>(binned, bbase, csr, row_start, dis);

  // conv1: y1 = half(dis*(x@w1)) -> yH; gather(store) -> h1raw=hB + stats1
  k_gemm<256, false><<<nblkG, 256, 0, stream>>>(x, w1, dis, nullptr, nullptr, nullptr, yH);
  k_gather<false><<<2048, 256, 0, stream>>>(csr, row_start, yH, dis, b1, hB, stats1,
                                            nullptr, nullptr, nullptr);

  // conv2: y2 = half(dis*(BN1(h1raw)@w2)) -> yH; gather(pool) -> sums/cnt + stats2
  k_gemm<64, true><<<nblkG, 256, 0, stream>>>(hB, w2, dis, stats1, g1, be1, yH);
  k_gather<true><<<2048, 256, 0, stream>>>(csr, row_start, yH, dis, b2, nullptr, stats2,
                                           batch, sums, cnt);

  // BN2-affine on pooled means + MLP head
  k_mlp<<<NG, 128, 0, stream>>>(sums, cnt, stats2, g2, be2,
                                fw1, fb1, fw2, fb2, fw3, fb3, fw4, fb4, ow, ob, out);
}